// Round 6
// baseline (429.482 us; speedup 1.0000x reference)
//
#include <hip/hip_runtime.h>

// GCN: 2x GCNConv(sym-norm, self-loops) + mean-pool + 2 MLP heads.
// R8: tile-phased aggA (R4's proven lockstep sweep) x 16B recompute
// operand Xp=(x0,x1,x2,dinv) (R5's compression). Per-phase gather window
// = 0.5MB, resident under streaming pressure. Non-temporal hints keep the
// edata stream / h2 stores from evicting the gather window.
// Lessons baked in: R2 no float LDS atomics (CAS storm); R3 no scattered
// global writes (L2 churn); R5 no unphased gathers (window thrash).

#define NBUCK 512          // coarse buckets = dst >> 9
#define BCAP  10240        // slack capacity per bucket (mean 8192, sigma ~90)
#define CHUNK 4096         // edges per pass-A block
#define NTILE 8            // src tiles = src >> 15
#define TSH   15
#define RCAP  20           // BCAP/512 register-staged edges per thread

__device__ __forceinline__ float leaky(float x) { return x > 0.f ? x : 0.01f * x; }

typedef float __attribute__((ext_vector_type(4))) f32x4;

__device__ __forceinline__ void nt_store4(float a, float b, float c, float d, float* dst) {
    f32x4 v = {a, b, c, d};
    __builtin_nontemporal_store(v, (f32x4*)dst);
}
// edata as read-once stream: 8B NT load, unpack (little-endian: lo=src)
__device__ __forceinline__ void nt_edge(const int2* p, int& s, float& w) {
    long long raw = __builtin_nontemporal_load((const long long*)p);
    s = (int)(unsigned)(raw & 0xFFFFFFFFll);
    w = __int_as_float((int)(raw >> 32));
}

// --- Pass A: bin edges by dst>>9 into slack-capacity coarse buckets ------
__global__ __launch_bounds__(256) void
binA_kernel(const int* __restrict__ src, const int* __restrict__ dst,
            const float* __restrict__ ew, int* __restrict__ bucketCursor,
            int2* __restrict__ coarse, int E) {
    __shared__ int lhist[NBUCK], lbase[NBUCK], lcur[NBUCK], gbase[NBUCK];
    __shared__ int tmp[256];
    __shared__ int2 stag[CHUNK];
    __shared__ unsigned short sbuck[CHUNK];
    int t = threadIdx.x;
    int base = blockIdx.x * CHUNK;
    for (int b = t; b < NBUCK; b += 256) { lhist[b] = 0; lcur[b] = 0; }
    __syncthreads();
    int n = min(CHUNK, E - base);
    int myDst[16], mySrc[16]; float myEw[16];
#pragma unroll
    for (int k = 0; k < 16; ++k) {
        int j = t + k * 256;                       // coalesced
        if (j < n) {
            int d = dst[base + j];
            myDst[k] = d; mySrc[k] = src[base + j]; myEw[k] = ew[base + j];
            atomicAdd(&lhist[d >> 9], 1);
        } else myDst[k] = -1;
    }
    __syncthreads();
    // exclusive scan of lhist (512 entries, 256 threads, pair trick)
    tmp[t] = lhist[2 * t] + lhist[2 * t + 1];
    __syncthreads();
    for (int off = 1; off < 256; off <<= 1) {
        int v = (t >= off) ? tmp[t - off] : 0;
        __syncthreads();
        tmp[t] += v;
        __syncthreads();
    }
    int pb = (t == 0) ? 0 : tmp[t - 1];
    lbase[2 * t] = pb;
    lbase[2 * t + 1] = pb + lhist[2 * t];
    __syncthreads();
    // reserve global space per bucket (one atomic per non-empty bucket)
    for (int b = t; b < NBUCK; b += 256) {
        int c = lhist[b];
        gbase[b] = c ? atomicAdd(&bucketCursor[b], c) : 0;
    }
    // stage into LDS, sorted by bucket; pack (src | ldst<<18, ew)
    for (int k = 0; k < 16; ++k) {
        int d = myDst[k];
        if (d >= 0) {
            int b = d >> 9;
            int p = lbase[b] + atomicAdd(&lcur[b], 1);
            stag[p] = make_int2(mySrc[k] | ((d & 511) << 18), __float_as_int(myEw[k]));
            sbuck[p] = (unsigned short)b;
        }
    }
    __syncthreads();
    // write out: consecutive j -> consecutive addresses within bucket runs
    for (int j = t; j < n; j += 256) {
        int b = sbuck[j];
        coarse[(size_t)b * BCAP + gbase[b] + (j - lbase[b])] = stag[j];
    }
}

// --- scan bucket counts -> bucket bases (1 block x 512) ------------------
__global__ void bscan_kernel(const int* __restrict__ bucketCursor,
                             int* __restrict__ bucketBase, int* __restrict__ row,
                             int N, int E) {
    __shared__ int s[NBUCK];
    int t = threadIdx.x;
    int v = bucketCursor[t];
    s[t] = v;
    __syncthreads();
    for (int off = 1; off < NBUCK; off <<= 1) {
        int x = (t >= off) ? s[t - off] : 0;
        __syncthreads();
        s[t] += x;
        __syncthreads();
    }
    bucketBase[t] = s[t] - v;
    if (t == 0) row[N] = E;
}

// --- Pass B: LDS-staged (ld,tile) counting sort; coalesced writeout ------
__global__ __launch_bounds__(512, 2) void
binB_kernel(const int* __restrict__ bucketCursor, const int* __restrict__ bucketBase,
            const int2* __restrict__ coarse, int2* __restrict__ edata,
            int* __restrict__ row, float* __restrict__ dinv,
            uint4* __restrict__ tcnt) {
    __shared__ int2 sedata[BCAP];         // 80 KB sort staging
    __shared__ int loff[NBUCK * NTILE];   // counts -> offsets -> cursors
    __shared__ int tmp[512];
    int b = blockIdx.x, t = threadIdx.x;
    for (int i = t; i < NBUCK * NTILE; i += 512) loff[i] = 0;
    __syncthreads();
    int cnt = bucketCursor[b];
    int gb  = bucketBase[b];
    const int2* cb = coarse + (size_t)b * BCAP;
    int2 myE[RCAP]; int myKey[RCAP];
#pragma unroll
    for (int k = 0; k < RCAP; ++k) {
        int j = t + k * 512;               // coalesced
        if (j < cnt) {
            int2 e = cb[j];
            myE[k] = e;
            myKey[k] = (((e.x >> 18) & 511) << 3) | ((e.x & 0x3FFFF) >> TSH);
            atomicAdd(&loff[myKey[k]], 1);
        } else myKey[k] = -1;
    }
    __syncthreads();
    // exclusive scan over 4096 (thread t owns node t's 8 tile-bins)
    int base8 = t * 8, s = 0;
#pragma unroll
    for (int k = 0; k < 8; ++k) s += loff[base8 + k];
    tmp[t] = s;
    __syncthreads();
    for (int off = 1; off < 512; off <<= 1) {
        int v = (t >= off) ? tmp[t - off] : 0;
        __syncthreads();
        tmp[t] += v;
        __syncthreads();
    }
    int run = tmp[t] - s;
    int o[9];
#pragma unroll
    for (int k = 0; k < 8; ++k) { int v = loff[base8 + k]; o[k] = run; loff[base8 + k] = run; run += v; }
    o[8] = run;                            // end of node t's edge range
    __syncthreads();
    int node = b * 512 + t;
    row[node] = gb + o[0];
    uint4 p;
    p.x = (unsigned)(o[1] - o[0]) | ((unsigned)(o[2] - o[1]) << 16);
    p.y = (unsigned)(o[3] - o[2]) | ((unsigned)(o[4] - o[3]) << 16);
    p.z = (unsigned)(o[5] - o[4]) | ((unsigned)(o[6] - o[5]) << 16);
    p.w = (unsigned)(o[7] - o[6]) | ((unsigned)(o[8] - o[7]) << 16);
    tcnt[node] = p;
    // place into LDS staging (loff is the moving cursor)
#pragma unroll
    for (int k = 0; k < RCAP; ++k) {
        if (myKey[k] >= 0) {
            int pos = atomicAdd(&loff[myKey[k]], 1);
            sedata[pos] = make_int2(myE[k].x & 0x3FFFF, myE[k].y);
        }
    }
    __syncthreads();
    // coalesced streaming writeout
    for (int j = t; j < cnt; j += 512) edata[gb + j] = sedata[j];
    // deg = sum of ew over this node's LDS-resident run
    float dsum = 0.f;
    for (int j = o[0]; j < o[8]; ++j) dsum += __int_as_float(sedata[j].y);
    dinv[node] = rsqrtf(1.0f + dsum);      // +1 = self-loop weight
}

// --- pack: Xp[i] = (x0, x1, x2, dinv) -- the 16B aggA gather operand -----
__global__ void pack_kernel(const float* __restrict__ X, const float* __restrict__ dinv,
                            float4* __restrict__ Xp, int N) {
    int i = blockIdx.x * blockDim.x + threadIdx.x;
    if (i >= N) return;
    Xp[i] = make_float4(X[3 * i], X[3 * i + 1], X[3 * i + 2], dinv[i]);
}

// --- agg pass 1: tile-phased 16B-gather recompute; fused node2 -----------
// 512 threads = 128 node-groups x 4 lanes; 2 nodes per group (i, i+128).
// All 1024 blocks co-resident (4/CU); per-tile barrier keeps each XCD's
// gathers inside a 0.5MB Xp window. edata NT-loaded (read-once stream).
__global__ __launch_bounds__(512) void
aggA_kernel(const int* __restrict__ row, const uint4* __restrict__ tcnt,
            const int2* __restrict__ edata, const float4* __restrict__ Xp,
            const float* __restrict__ W1, const float* __restrict__ b1,
            const float* __restrict__ W2, float* __restrict__ h2) {
    __shared__ float w1s[48];
    __shared__ float w[256];
    __shared__ float bb[16];
    __shared__ float sx[128][17];
    int t = threadIdx.x;
    if (t < 256) w[t] = W2[t];
    else if (t < 272) bb[t - 256] = b1[t - 256];
    else if (t >= 288 && t < 336) w1s[t - 288] = W1[t - 288];
    __syncthreads();
    int ln = t >> 2, l = t & 3;
    // my 4 output features' W1 columns (3 input rows)
    float w1r0[4], w1r1[4], w1r2[4];
#pragma unroll
    for (int c = 0; c < 4; ++c) {
        w1r0[c] = w1s[0 * 16 + 4 * l + c];
        w1r1[c] = w1s[1 * 16 + 4 * l + c];
        w1r2[c] = w1s[2 * 16 + 4 * l + c];
    }
    int iA = blockIdx.x * 256 + ln, iB = iA + 128;
    int eA = row[iA], eB = row[iB];
    uint4 cAv = tcnt[iA], cBv = tcnt[iB];
    unsigned ca[4] = {cAv.x, cAv.y, cAv.z, cAv.w};
    unsigned cb[4] = {cBv.x, cBv.y, cBv.z, cBv.w};
    float4 xpA = Xp[iA], xpB = Xp[iB];
    float diA = xpA.w, diB = xpB.w;
    float accA[4], accB[4];
#pragma unroll
    for (int c = 0; c < 4; ++c) {   // self-loop seed: h'_i = (X_i@W1)*dinv_i
        accA[c] = (xpA.x * w1r0[c] + xpA.y * w1r1[c] + xpA.z * w1r2[c]) * diA;
        accB[c] = (xpB.x * w1r0[c] + xpB.y * w1r1[c] + xpB.z * w1r2[c]) * diB;
    }
#pragma unroll
    for (int tt = 0; tt < NTILE; ++tt) {
        int nA = (ca[tt >> 1] >> ((tt & 1) * 16)) & 0xFFFF;
        int nB = (cb[tt >> 1] >> ((tt & 1) * 16)) & 0xFFFF;
        for (int e = eA + nA; eA < e; ++eA) {
            int s; float ewv; nt_edge(edata + eA, s, ewv);
            float4 xs = Xp[s];
            float f = ewv * xs.w;
            float f0 = xs.x * f, f1 = xs.y * f, f2 = xs.z * f;
#pragma unroll
            for (int c = 0; c < 4; ++c)
                accA[c] += f0 * w1r0[c] + f1 * w1r1[c] + f2 * w1r2[c];
        }
        for (int e = eB + nB; eB < e; ++eB) {
            int s; float ewv; nt_edge(edata + eB, s, ewv);
            float4 xs = Xp[s];
            float f = ewv * xs.w;
            float f0 = xs.x * f, f1 = xs.y * f, f2 = xs.z * f;
#pragma unroll
            for (int c = 0; c < 4; ++c)
                accB[c] += f0 * w1r0[c] + f1 * w1r1[c] + f2 * w1r2[c];
        }
        __syncthreads();
    }
    // fused node2: x = leaky(di*acc + b1); h2' = (x@W2)*di (LDS transpose)
    sx[ln][4 * l + 0] = leaky(diA * accA[0] + bb[4 * l + 0]);
    sx[ln][4 * l + 1] = leaky(diA * accA[1] + bb[4 * l + 1]);
    sx[ln][4 * l + 2] = leaky(diA * accA[2] + bb[4 * l + 2]);
    sx[ln][4 * l + 3] = leaky(diA * accA[3] + bb[4 * l + 3]);
    __syncthreads();
    {
        float a0 = 0.f, a1 = 0.f, a2 = 0.f, a3 = 0.f;
#pragma unroll
        for (int q = 0; q < 16; ++q) {
            float xv = sx[ln][q];
            a0 += xv * w[q * 16 + 4 * l + 0];
            a1 += xv * w[q * 16 + 4 * l + 1];
            a2 += xv * w[q * 16 + 4 * l + 2];
            a3 += xv * w[q * 16 + 4 * l + 3];
        }
        nt_store4(a0 * diA, a1 * diA, a2 * diA, a3 * diA, h2 + (size_t)iA * 16 + l * 4);
    }
    __syncthreads();
    sx[ln][4 * l + 0] = leaky(diB * accB[0] + bb[4 * l + 0]);
    sx[ln][4 * l + 1] = leaky(diB * accB[1] + bb[4 * l + 1]);
    sx[ln][4 * l + 2] = leaky(diB * accB[2] + bb[4 * l + 2]);
    sx[ln][4 * l + 3] = leaky(diB * accB[3] + bb[4 * l + 3]);
    __syncthreads();
    {
        float a0 = 0.f, a1 = 0.f, a2 = 0.f, a3 = 0.f;
#pragma unroll
        for (int q = 0; q < 16; ++q) {
            float xv = sx[ln][q];
            a0 += xv * w[q * 16 + 4 * l + 0];
            a1 += xv * w[q * 16 + 4 * l + 1];
            a2 += xv * w[q * 16 + 4 * l + 2];
            a3 += xv * w[q * 16 + 4 * l + 3];
        }
        nt_store4(a0 * diB, a1 * diB, a2 * diB, a3 * diB, h2 + (size_t)iB * 16 + l * 4);
    }
}

// --- agg pass 2, tile-phased 64B gather (pool applies b2+leaky) ----------
__global__ __launch_bounds__(512) void
aggB_kernel(const int* __restrict__ row, const uint4* __restrict__ tcnt,
            const int2* __restrict__ edata, const float* __restrict__ dinv,
            const float* __restrict__ h2prime, float* __restrict__ agg2) {
    int t = threadIdx.x;
    int ln = t >> 2, l = t & 3;
    int iA = blockIdx.x * 256 + ln, iB = iA + 128;
    const float4* hp = (const float4*)h2prime;
    int eA = row[iA], eB = row[iB];
    uint4 cAv = tcnt[iA], cBv = tcnt[iB];
    unsigned ca[4] = {cAv.x, cAv.y, cAv.z, cAv.w};
    unsigned cb[4] = {cBv.x, cBv.y, cBv.z, cBv.w};
    float diA = dinv[iA], diB = dinv[iB];
    float4 accA = hp[(size_t)iA * 4 + l];    // self-loop seed (h2')
    float4 accB = hp[(size_t)iB * 4 + l];
#pragma unroll
    for (int tt = 0; tt < NTILE; ++tt) {
        int nA = (ca[tt >> 1] >> ((tt & 1) * 16)) & 0xFFFF;
        int nB = (cb[tt >> 1] >> ((tt & 1) * 16)) & 0xFFFF;
        for (int e = eA + nA; eA < e; ++eA) {
            int s; float ewv; nt_edge(edata + eA, s, ewv);
            float4 v = hp[(size_t)s * 4 + l];
            accA.x += v.x * ewv; accA.y += v.y * ewv;
            accA.z += v.z * ewv; accA.w += v.w * ewv;
        }
        for (int e = eB + nB; eB < e; ++eB) {
            int s; float ewv; nt_edge(edata + eB, s, ewv);
            float4 v = hp[(size_t)s * 4 + l];
            accB.x += v.x * ewv; accB.y += v.y * ewv;
            accB.z += v.z * ewv; accB.w += v.w * ewv;
        }
        __syncthreads();
    }
    nt_store4(accA.x * diA, accA.y * diA, accA.z * diA, accA.w * diA,
              agg2 + (size_t)iA * 16 + l * 4);
    nt_store4(accB.x * diB, accB.y * diB, accB.z * diB, accB.w * diB,
              agg2 + (size_t)iB * 16 + l * 4);
}

// --- tiny MLP head: 16 ->16 ->16 ->2 -------------------------------------
__device__ void head_mlp(const float* pooled,
                         const float* __restrict__ Wa, const float* __restrict__ ba,
                         const float* __restrict__ Wb, const float* __restrict__ bb,
                         const float* __restrict__ Wc, const float* __restrict__ bc,
                         float* o) {
    float t[16], u[16];
#pragma unroll
    for (int f = 0; f < 16; ++f) {
        float a = ba[f];
        for (int k = 0; k < 16; ++k) a += pooled[k] * Wa[k * 16 + f];
        t[f] = leaky(a);
    }
#pragma unroll
    for (int f = 0; f < 16; ++f) {
        float a = bb[f];
        for (int k = 0; k < 16; ++k) a += t[k] * Wb[k * 16 + f];
        u[f] = leaky(a);
    }
    float o0 = bc[0], o1 = bc[1];
    for (int k = 0; k < 16; ++k) { o0 += u[k] * Wc[2 * k]; o1 += u[k] * Wc[2 * k + 1]; }
    o[0] = o0; o[1] = o1;
}

// --- pool (block per graph; Batching sorted -> binary search) + heads ----
__global__ void pool_head_kernel(const float* __restrict__ agg2, const float* __restrict__ b2,
                                 const int* __restrict__ batching, int N,
                                 const float* __restrict__ Wp1, const float* __restrict__ bp1,
                                 const float* __restrict__ Wp2, const float* __restrict__ bp2,
                                 const float* __restrict__ Wp3, const float* __restrict__ bp3,
                                 const float* __restrict__ Wt1, const float* __restrict__ bt1,
                                 const float* __restrict__ Wt2, const float* __restrict__ bt2,
                                 const float* __restrict__ Wt3, const float* __restrict__ bt3,
                                 float* __restrict__ out) {
    int g = blockIdx.x;
    __shared__ int bounds[2];
    if (threadIdx.x < 2) {
        int v = g + (int)threadIdx.x;
        int lo = 0, hi = N;
        while (lo < hi) { int m = (lo + hi) >> 1; if (batching[m] < v) lo = m + 1; else hi = m; }
        bounds[threadIdx.x] = lo;
    }
    __syncthreads();
    int lo = bounds[0], hi = bounds[1];
    int f = threadIdx.x & 15, r = threadIdx.x >> 4;    // 16 rows x 16 features
    float bf = b2[f];
    float acc = 0.f;
    for (int i = lo + r; i < hi; i += 16) acc += leaky(agg2[(size_t)i * 16 + f] + bf);
    __shared__ float red[16][17];
    red[r][f] = acc;
    __syncthreads();
    __shared__ float pooled[16];
    if (r == 0) {
        float s = 0.f;
#pragma unroll
        for (int k = 0; k < 16; ++k) s += red[k][f];
        pooled[f] = s / fmaxf((float)(hi - lo), 1.0f);
    }
    __syncthreads();
    if (threadIdx.x == 0) {
        float o[2];
        head_mlp(pooled, Wp1, bp1, Wp2, bp2, Wp3, bp3, o);
        out[4 * g + 0] = o[0]; out[4 * g + 1] = o[1];
    } else if (threadIdx.x == 1) {
        float o[2];
        head_mlp(pooled, Wt1, bt1, Wt2, bt2, Wt3, bt3, o);
        out[4 * g + 2] = o[0]; out[4 * g + 3] = o[1];
    }
}

extern "C" void kernel_launch(void* const* d_in, const int* in_sizes, int n_in,
                              void* d_out, int out_size, void* d_ws, size_t ws_size,
                              hipStream_t stream) {
    const float* X        = (const float*)d_in[0];
    const int*   ei       = (const int*)d_in[1];
    const float* ew       = (const float*)d_in[2];
    const int*   batching = (const int*)d_in[3];
    const float* W1  = (const float*)d_in[5];  const float* b1  = (const float*)d_in[6];
    const float* W2  = (const float*)d_in[7];  const float* b2  = (const float*)d_in[8];
    const float* Wp1 = (const float*)d_in[9];  const float* bp1 = (const float*)d_in[10];
    const float* Wp2 = (const float*)d_in[11]; const float* bp2 = (const float*)d_in[12];
    const float* Wp3 = (const float*)d_in[13]; const float* bp3 = (const float*)d_in[14];
    const float* Wt1 = (const float*)d_in[15]; const float* bt1 = (const float*)d_in[16];
    const float* Wt2 = (const float*)d_in[17]; const float* bt2 = (const float*)d_in[18];
    const float* Wt3 = (const float*)d_in[19]; const float* bt3 = (const float*)d_in[20];

    const int N = in_sizes[3];        // 262144 = 512 * 512
    const int E = in_sizes[2];        // 4194304
    const int G = out_size / 4;       // 1024
    const int* src = ei;
    const int* dst = ei + E;

    char* ws = (char*)d_ws;
    size_t off = 0;
    int2*  edata = (int2*)(ws + off);  off += (size_t)E * 8;              // 32 MB fine CSR
    char*  regionA = ws + off;         off += (size_t)N * 64 * 3;         // 48 MB
    // regionA phase 1: coarse buckets (40 MB); phase 2: h2' | agg2 | Xp
    // (pack/aggA run only after binB has consumed coarse)
    int2*  coarse = (int2*)regionA;
    float* h2     = (float*)regionA;
    float* agg2   = (float*)(regionA + (size_t)N * 64);
    float4* Xp    = (float4*)(regionA + (size_t)N * 128);                 // 4 MB
    int*   bucketCursor = (int*)(ws + off); off += NBUCK * 4;
    int*   bucketBase   = (int*)(ws + off); off += NBUCK * 4;
    int*   row   = (int*)(ws + off);   off += (size_t)(N + 4) * 4;
    float* dinv  = (float*)(ws + off); off += (size_t)N * 4;
    uint4* tcnt  = (uint4*)(ws + off); off += (size_t)N * 16;             // 4 MB
    float* out   = (float*)d_out;

    hipMemsetAsync(bucketCursor, 0, NBUCK * 4, stream);

    const int tb = 256;
    binA_kernel<<<(E + CHUNK - 1) / CHUNK, tb, 0, stream>>>(src, dst, ew, bucketCursor, coarse, E);
    bscan_kernel<<<1, NBUCK, 0, stream>>>(bucketCursor, bucketBase, row, N, E);
    binB_kernel<<<NBUCK, 512, 0, stream>>>(bucketCursor, bucketBase, coarse, edata, row, dinv, tcnt);
    pack_kernel<<<(N + tb - 1) / tb, tb, 0, stream>>>(X, dinv, Xp, N);
    aggA_kernel<<<N / 256, 512, 0, stream>>>(row, tcnt, edata, Xp, W1, b1, W2, h2);
    aggB_kernel<<<N / 256, 512, 0, stream>>>(row, tcnt, edata, dinv, h2, agg2);
    pool_head_kernel<<<G, tb, 0, stream>>>(agg2, b2, batching, N,
                                           Wp1, bp1, Wp2, bp2, Wp3, bp3,
                                           Wt1, bt1, Wt2, bt2, Wt3, bt3, out);
}

// Round 7
// 348.364 us; speedup vs baseline: 1.2329x; 1.2329x over previous
//
#include <hip/hip_runtime.h>

// GCN: 2x GCNConv(sym-norm, self-loops) + mean-pool + 2 MLP heads.
// R9: (a) ALL non-temporal hints removed -- R6 lesson: NT store on h2
// evicted aggB's gather operand from L2 (FETCH 207->278MB, +36us).
// (b) aggA keeps R6's tile-phased sweep with 16B recompute operand
// Xp=(x0,x1,x2,dinv), now with plain loads. (c) binA CHUNK 4096->8192
// (512 thr): per-bucket write runs go 8->16 edges = full 128B lines,
// halving the R3-style partial-line scatter churn on coarse[].
// Standing lessons: R2 no float LDS atomics; R3/R4 sort in LDS + write
// coalesced; R5 gathers must be tile-phase-synchronized.

#define NBUCK 512          // coarse buckets = dst >> 9
#define BCAP  10240        // slack capacity per bucket (mean 8192, sigma ~90)
#define CHUNK 8192         // edges per pass-A block (16 per bucket avg)
#define APT   16           // edges per thread in binA (CHUNK/512)
#define NTILE 8            // src tiles = src >> 15
#define TSH   15
#define RCAP  20           // BCAP/512 register-staged edges per thread

__device__ __forceinline__ float leaky(float x) { return x > 0.f ? x : 0.01f * x; }

// --- Pass A: bin edges by dst>>9 into slack-capacity coarse buckets ------
__global__ __launch_bounds__(512) void
binA_kernel(const int* __restrict__ src, const int* __restrict__ dst,
            const float* __restrict__ ew, int* __restrict__ bucketCursor,
            int2* __restrict__ coarse, int E) {
    __shared__ int lhist[NBUCK], lbase[NBUCK], lcur[NBUCK], gbase[NBUCK];
    __shared__ int tmp[NBUCK];
    __shared__ int2 stag[CHUNK];              // 64 KB
    __shared__ unsigned short sbuck[CHUNK];   // 16 KB
    int t = threadIdx.x;
    int base = blockIdx.x * CHUNK;
    lhist[t] = 0; lcur[t] = 0;
    __syncthreads();
    int n = min(CHUNK, E - base);
    int myDst[APT], mySrc[APT]; float myEw[APT];
#pragma unroll
    for (int k = 0; k < APT; ++k) {
        int j = t + k * 512;                  // coalesced
        if (j < n) {
            int d = dst[base + j];
            myDst[k] = d; mySrc[k] = src[base + j]; myEw[k] = ew[base + j];
            atomicAdd(&lhist[d >> 9], 1);
        } else myDst[k] = -1;
    }
    __syncthreads();
    // exclusive scan of lhist (512 entries, 512 threads)
    int hv = lhist[t];
    tmp[t] = hv;
    __syncthreads();
    for (int off = 1; off < NBUCK; off <<= 1) {
        int v = (t >= off) ? tmp[t - off] : 0;
        __syncthreads();
        tmp[t] += v;
        __syncthreads();
    }
    lbase[t] = tmp[t] - hv;
    gbase[t] = hv ? atomicAdd(&bucketCursor[t], hv) : 0;
    __syncthreads();
    // stage into LDS, sorted by bucket; pack (src | ldst<<18, ew)
#pragma unroll
    for (int k = 0; k < APT; ++k) {
        int d = myDst[k];
        if (d >= 0) {
            int b = d >> 9;
            int p = lbase[b] + atomicAdd(&lcur[b], 1);
            stag[p] = make_int2(mySrc[k] | ((d & 511) << 18), __float_as_int(myEw[k]));
            sbuck[p] = (unsigned short)b;
        }
    }
    __syncthreads();
    // write out: consecutive j -> consecutive addresses within bucket runs
    for (int j = t; j < n; j += 512) {
        int b = sbuck[j];
        coarse[(size_t)b * BCAP + gbase[b] + (j - lbase[b])] = stag[j];
    }
}

// --- scan bucket counts -> bucket bases (1 block x 512) ------------------
__global__ void bscan_kernel(const int* __restrict__ bucketCursor,
                             int* __restrict__ bucketBase, int* __restrict__ row,
                             int N, int E) {
    __shared__ int s[NBUCK];
    int t = threadIdx.x;
    int v = bucketCursor[t];
    s[t] = v;
    __syncthreads();
    for (int off = 1; off < NBUCK; off <<= 1) {
        int x = (t >= off) ? s[t - off] : 0;
        __syncthreads();
        s[t] += x;
        __syncthreads();
    }
    bucketBase[t] = s[t] - v;
    if (t == 0) row[N] = E;
}

// --- Pass B: LDS-staged (ld,tile) counting sort; coalesced writeout ------
__global__ __launch_bounds__(512, 2) void
binB_kernel(const int* __restrict__ bucketCursor, const int* __restrict__ bucketBase,
            const int2* __restrict__ coarse, int2* __restrict__ edata,
            int* __restrict__ row, float* __restrict__ dinv,
            uint4* __restrict__ tcnt) {
    __shared__ int2 sedata[BCAP];         // 80 KB sort staging
    __shared__ int loff[NBUCK * NTILE];   // counts -> offsets -> cursors
    __shared__ int tmp[512];
    int b = blockIdx.x, t = threadIdx.x;
    for (int i = t; i < NBUCK * NTILE; i += 512) loff[i] = 0;
    __syncthreads();
    int cnt = bucketCursor[b];
    int gb  = bucketBase[b];
    const int2* cb = coarse + (size_t)b * BCAP;
    int2 myE[RCAP]; int myKey[RCAP];
#pragma unroll
    for (int k = 0; k < RCAP; ++k) {
        int j = t + k * 512;               // coalesced
        if (j < cnt) {
            int2 e = cb[j];
            myE[k] = e;
            myKey[k] = (((e.x >> 18) & 511) << 3) | ((e.x & 0x3FFFF) >> TSH);
            atomicAdd(&loff[myKey[k]], 1);
        } else myKey[k] = -1;
    }
    __syncthreads();
    // exclusive scan over 4096 (thread t owns node t's 8 tile-bins)
    int base8 = t * 8, s = 0;
#pragma unroll
    for (int k = 0; k < 8; ++k) s += loff[base8 + k];
    tmp[t] = s;
    __syncthreads();
    for (int off = 1; off < 512; off <<= 1) {
        int v = (t >= off) ? tmp[t - off] : 0;
        __syncthreads();
        tmp[t] += v;
        __syncthreads();
    }
    int run = tmp[t] - s;
    int o[9];
#pragma unroll
    for (int k = 0; k < 8; ++k) { int v = loff[base8 + k]; o[k] = run; loff[base8 + k] = run; run += v; }
    o[8] = run;                            // end of node t's edge range
    __syncthreads();
    int node = b * 512 + t;
    row[node] = gb + o[0];
    uint4 p;
    p.x = (unsigned)(o[1] - o[0]) | ((unsigned)(o[2] - o[1]) << 16);
    p.y = (unsigned)(o[3] - o[2]) | ((unsigned)(o[4] - o[3]) << 16);
    p.z = (unsigned)(o[5] - o[4]) | ((unsigned)(o[6] - o[5]) << 16);
    p.w = (unsigned)(o[7] - o[6]) | ((unsigned)(o[8] - o[7]) << 16);
    tcnt[node] = p;
    // place into LDS staging (loff is the moving cursor)
#pragma unroll
    for (int k = 0; k < RCAP; ++k) {
        if (myKey[k] >= 0) {
            int pos = atomicAdd(&loff[myKey[k]], 1);
            sedata[pos] = make_int2(myE[k].x & 0x3FFFF, myE[k].y);
        }
    }
    __syncthreads();
    // coalesced streaming writeout
    for (int j = t; j < cnt; j += 512) edata[gb + j] = sedata[j];
    // deg = sum of ew over this node's LDS-resident run
    float dsum = 0.f;
    for (int j = o[0]; j < o[8]; ++j) dsum += __int_as_float(sedata[j].y);
    dinv[node] = rsqrtf(1.0f + dsum);      // +1 = self-loop weight
}

// --- pack: Xp[i] = (x0, x1, x2, dinv) -- the 16B aggA gather operand -----
__global__ void pack_kernel(const float* __restrict__ X, const float* __restrict__ dinv,
                            float4* __restrict__ Xp, int N) {
    int i = blockIdx.x * blockDim.x + threadIdx.x;
    if (i >= N) return;
    Xp[i] = make_float4(X[3 * i], X[3 * i + 1], X[3 * i + 2], dinv[i]);
}

// --- agg pass 1: tile-phased 16B-gather recompute; fused node2 -----------
// 512 threads = 128 node-groups x 4 lanes; 2 nodes per group (i, i+128).
// All 1024 blocks co-resident (4/CU); per-tile barrier keeps each XCD's
// gathers inside a 0.5MB Xp window.
__global__ __launch_bounds__(512) void
aggA_kernel(const int* __restrict__ row, const uint4* __restrict__ tcnt,
            const int2* __restrict__ edata, const float4* __restrict__ Xp,
            const float* __restrict__ W1, const float* __restrict__ b1,
            const float* __restrict__ W2, float* __restrict__ h2) {
    __shared__ float w1s[48];
    __shared__ float w[256];
    __shared__ float bb[16];
    __shared__ float sx[128][17];
    int t = threadIdx.x;
    if (t < 256) w[t] = W2[t];
    else if (t < 272) bb[t - 256] = b1[t - 256];
    else if (t >= 288 && t < 336) w1s[t - 288] = W1[t - 288];
    __syncthreads();
    int ln = t >> 2, l = t & 3;
    // my 4 output features' W1 columns (3 input rows)
    float w1r0[4], w1r1[4], w1r2[4];
#pragma unroll
    for (int c = 0; c < 4; ++c) {
        w1r0[c] = w1s[0 * 16 + 4 * l + c];
        w1r1[c] = w1s[1 * 16 + 4 * l + c];
        w1r2[c] = w1s[2 * 16 + 4 * l + c];
    }
    int iA = blockIdx.x * 256 + ln, iB = iA + 128;
    int eA = row[iA], eB = row[iB];
    uint4 cAv = tcnt[iA], cBv = tcnt[iB];
    unsigned ca[4] = {cAv.x, cAv.y, cAv.z, cAv.w};
    unsigned cb[4] = {cBv.x, cBv.y, cBv.z, cBv.w};
    float4 xpA = Xp[iA], xpB = Xp[iB];
    float diA = xpA.w, diB = xpB.w;
    float accA[4], accB[4];
#pragma unroll
    for (int c = 0; c < 4; ++c) {   // self-loop seed: h'_i = (X_i@W1)*dinv_i
        accA[c] = (xpA.x * w1r0[c] + xpA.y * w1r1[c] + xpA.z * w1r2[c]) * diA;
        accB[c] = (xpB.x * w1r0[c] + xpB.y * w1r1[c] + xpB.z * w1r2[c]) * diB;
    }
#pragma unroll
    for (int tt = 0; tt < NTILE; ++tt) {
        int nA = (ca[tt >> 1] >> ((tt & 1) * 16)) & 0xFFFF;
        int nB = (cb[tt >> 1] >> ((tt & 1) * 16)) & 0xFFFF;
        for (int e = eA + nA; eA < e; ++eA) {
            int2 ed = edata[eA];
            float4 xs = Xp[ed.x];
            float f = __int_as_float(ed.y) * xs.w;
            float f0 = xs.x * f, f1 = xs.y * f, f2 = xs.z * f;
#pragma unroll
            for (int c = 0; c < 4; ++c)
                accA[c] += f0 * w1r0[c] + f1 * w1r1[c] + f2 * w1r2[c];
        }
        for (int e = eB + nB; eB < e; ++eB) {
            int2 ed = edata[eB];
            float4 xs = Xp[ed.x];
            float f = __int_as_float(ed.y) * xs.w;
            float f0 = xs.x * f, f1 = xs.y * f, f2 = xs.z * f;
#pragma unroll
            for (int c = 0; c < 4; ++c)
                accB[c] += f0 * w1r0[c] + f1 * w1r1[c] + f2 * w1r2[c];
        }
        __syncthreads();
    }
    // fused node2: x = leaky(di*acc + b1); h2' = (x@W2)*di (LDS transpose)
    sx[ln][4 * l + 0] = leaky(diA * accA[0] + bb[4 * l + 0]);
    sx[ln][4 * l + 1] = leaky(diA * accA[1] + bb[4 * l + 1]);
    sx[ln][4 * l + 2] = leaky(diA * accA[2] + bb[4 * l + 2]);
    sx[ln][4 * l + 3] = leaky(diA * accA[3] + bb[4 * l + 3]);
    __syncthreads();
    {
        float a0 = 0.f, a1 = 0.f, a2 = 0.f, a3 = 0.f;
#pragma unroll
        for (int q = 0; q < 16; ++q) {
            float xv = sx[ln][q];
            a0 += xv * w[q * 16 + 4 * l + 0];
            a1 += xv * w[q * 16 + 4 * l + 1];
            a2 += xv * w[q * 16 + 4 * l + 2];
            a3 += xv * w[q * 16 + 4 * l + 3];
        }
        ((float4*)h2)[(size_t)iA * 4 + l] = make_float4(a0 * diA, a1 * diA, a2 * diA, a3 * diA);
    }
    __syncthreads();
    sx[ln][4 * l + 0] = leaky(diB * accB[0] + bb[4 * l + 0]);
    sx[ln][4 * l + 1] = leaky(diB * accB[1] + bb[4 * l + 1]);
    sx[ln][4 * l + 2] = leaky(diB * accB[2] + bb[4 * l + 2]);
    sx[ln][4 * l + 3] = leaky(diB * accB[3] + bb[4 * l + 3]);
    __syncthreads();
    {
        float a0 = 0.f, a1 = 0.f, a2 = 0.f, a3 = 0.f;
#pragma unroll
        for (int q = 0; q < 16; ++q) {
            float xv = sx[ln][q];
            a0 += xv * w[q * 16 + 4 * l + 0];
            a1 += xv * w[q * 16 + 4 * l + 1];
            a2 += xv * w[q * 16 + 4 * l + 2];
            a3 += xv * w[q * 16 + 4 * l + 3];
        }
        ((float4*)h2)[(size_t)iB * 4 + l] = make_float4(a0 * diB, a1 * diB, a2 * diB, a3 * diB);
    }
}

// --- agg pass 2, tile-phased 64B gather (pool applies b2+leaky) ----------
__global__ __launch_bounds__(512) void
aggB_kernel(const int* __restrict__ row, const uint4* __restrict__ tcnt,
            const int2* __restrict__ edata, const float* __restrict__ dinv,
            const float* __restrict__ h2prime, float* __restrict__ agg2) {
    int t = threadIdx.x;
    int ln = t >> 2, l = t & 3;
    int iA = blockIdx.x * 256 + ln, iB = iA + 128;
    const float4* hp = (const float4*)h2prime;
    int eA = row[iA], eB = row[iB];
    uint4 cAv = tcnt[iA], cBv = tcnt[iB];
    unsigned ca[4] = {cAv.x, cAv.y, cAv.z, cAv.w};
    unsigned cb[4] = {cBv.x, cBv.y, cBv.z, cBv.w};
    float diA = dinv[iA], diB = dinv[iB];
    float4 accA = hp[(size_t)iA * 4 + l];    // self-loop seed (h2')
    float4 accB = hp[(size_t)iB * 4 + l];
#pragma unroll
    for (int tt = 0; tt < NTILE; ++tt) {
        int nA = (ca[tt >> 1] >> ((tt & 1) * 16)) & 0xFFFF;
        int nB = (cb[tt >> 1] >> ((tt & 1) * 16)) & 0xFFFF;
        for (int e = eA + nA; eA < e; ++eA) {
            int2 ed = edata[eA];
            float ewv = __int_as_float(ed.y);
            float4 v = hp[(size_t)ed.x * 4 + l];
            accA.x += v.x * ewv; accA.y += v.y * ewv;
            accA.z += v.z * ewv; accA.w += v.w * ewv;
        }
        for (int e = eB + nB; eB < e; ++eB) {
            int2 ed = edata[eB];
            float ewv = __int_as_float(ed.y);
            float4 v = hp[(size_t)ed.x * 4 + l];
            accB.x += v.x * ewv; accB.y += v.y * ewv;
            accB.z += v.z * ewv; accB.w += v.w * ewv;
        }
        __syncthreads();
    }
    ((float4*)agg2)[(size_t)iA * 4 + l] =
        make_float4(accA.x * diA, accA.y * diA, accA.z * diA, accA.w * diA);
    ((float4*)agg2)[(size_t)iB * 4 + l] =
        make_float4(accB.x * diB, accB.y * diB, accB.z * diB, accB.w * diB);
}

// --- tiny MLP head: 16 ->16 ->16 ->2 -------------------------------------
__device__ void head_mlp(const float* pooled,
                         const float* __restrict__ Wa, const float* __restrict__ ba,
                         const float* __restrict__ Wb, const float* __restrict__ bb,
                         const float* __restrict__ Wc, const float* __restrict__ bc,
                         float* o) {
    float t[16], u[16];
#pragma unroll
    for (int f = 0; f < 16; ++f) {
        float a = ba[f];
        for (int k = 0; k < 16; ++k) a += pooled[k] * Wa[k * 16 + f];
        t[f] = leaky(a);
    }
#pragma unroll
    for (int f = 0; f < 16; ++f) {
        float a = bb[f];
        for (int k = 0; k < 16; ++k) a += t[k] * Wb[k * 16 + f];
        u[f] = leaky(a);
    }
    float o0 = bc[0], o1 = bc[1];
    for (int k = 0; k < 16; ++k) { o0 += u[k] * Wc[2 * k]; o1 += u[k] * Wc[2 * k + 1]; }
    o[0] = o0; o[1] = o1;
}

// --- pool (block per graph; Batching sorted -> binary search) + heads ----
__global__ void pool_head_kernel(const float* __restrict__ agg2, const float* __restrict__ b2,
                                 const int* __restrict__ batching, int N,
                                 const float* __restrict__ Wp1, const float* __restrict__ bp1,
                                 const float* __restrict__ Wp2, const float* __restrict__ bp2,
                                 const float* __restrict__ Wp3, const float* __restrict__ bp3,
                                 const float* __restrict__ Wt1, const float* __restrict__ bt1,
                                 const float* __restrict__ Wt2, const float* __restrict__ bt2,
                                 const float* __restrict__ Wt3, const float* __restrict__ bt3,
                                 float* __restrict__ out) {
    int g = blockIdx.x;
    __shared__ int bounds[2];
    if (threadIdx.x < 2) {
        int v = g + (int)threadIdx.x;
        int lo = 0, hi = N;
        while (lo < hi) { int m = (lo + hi) >> 1; if (batching[m] < v) lo = m + 1; else hi = m; }
        bounds[threadIdx.x] = lo;
    }
    __syncthreads();
    int lo = bounds[0], hi = bounds[1];
    int f = threadIdx.x & 15, r = threadIdx.x >> 4;    // 16 rows x 16 features
    float bf = b2[f];
    float acc = 0.f;
    for (int i = lo + r; i < hi; i += 16) acc += leaky(agg2[(size_t)i * 16 + f] + bf);
    __shared__ float red[16][17];
    red[r][f] = acc;
    __syncthreads();
    __shared__ float pooled[16];
    if (r == 0) {
        float s = 0.f;
#pragma unroll
        for (int k = 0; k < 16; ++k) s += red[k][f];
        pooled[f] = s / fmaxf((float)(hi - lo), 1.0f);
    }
    __syncthreads();
    if (threadIdx.x == 0) {
        float o[2];
        head_mlp(pooled, Wp1, bp1, Wp2, bp2, Wp3, bp3, o);
        out[4 * g + 0] = o[0]; out[4 * g + 1] = o[1];
    } else if (threadIdx.x == 1) {
        float o[2];
        head_mlp(pooled, Wt1, bt1, Wt2, bt2, Wt3, bt3, o);
        out[4 * g + 2] = o[0]; out[4 * g + 3] = o[1];
    }
}

extern "C" void kernel_launch(void* const* d_in, const int* in_sizes, int n_in,
                              void* d_out, int out_size, void* d_ws, size_t ws_size,
                              hipStream_t stream) {
    const float* X        = (const float*)d_in[0];
    const int*   ei       = (const int*)d_in[1];
    const float* ew       = (const float*)d_in[2];
    const int*   batching = (const int*)d_in[3];
    const float* W1  = (const float*)d_in[5];  const float* b1  = (const float*)d_in[6];
    const float* W2  = (const float*)d_in[7];  const float* b2  = (const float*)d_in[8];
    const float* Wp1 = (const float*)d_in[9];  const float* bp1 = (const float*)d_in[10];
    const float* Wp2 = (const float*)d_in[11]; const float* bp2 = (const float*)d_in[12];
    const float* Wp3 = (const float*)d_in[13]; const float* bp3 = (const float*)d_in[14];
    const float* Wt1 = (const float*)d_in[15]; const float* bt1 = (const float*)d_in[16];
    const float* Wt2 = (const float*)d_in[17]; const float* bt2 = (const float*)d_in[18];
    const float* Wt3 = (const float*)d_in[19]; const float* bt3 = (const float*)d_in[20];

    const int N = in_sizes[3];        // 262144 = 512 * 512
    const int E = in_sizes[2];        // 4194304
    const int G = out_size / 4;       // 1024
    const int* src = ei;
    const int* dst = ei + E;

    char* ws = (char*)d_ws;
    size_t off = 0;
    int2*  edata = (int2*)(ws + off);  off += (size_t)E * 8;              // 32 MB fine CSR
    char*  regionA = ws + off;         off += (size_t)N * 64 * 3;         // 48 MB
    // regionA phase 1: coarse buckets (40 MB); phase 2: h2' | agg2 | Xp
    // (pack/aggA run only after binB has consumed coarse)
    int2*  coarse = (int2*)regionA;
    float* h2     = (float*)regionA;
    float* agg2   = (float*)(regionA + (size_t)N * 64);
    float4* Xp    = (float4*)(regionA + (size_t)N * 128);                 // 4 MB
    int*   bucketCursor = (int*)(ws + off); off += NBUCK * 4;
    int*   bucketBase   = (int*)(ws + off); off += NBUCK * 4;
    int*   row   = (int*)(ws + off);   off += (size_t)(N + 4) * 4;
    float* dinv  = (float*)(ws + off); off += (size_t)N * 4;
    uint4* tcnt  = (uint4*)(ws + off); off += (size_t)N * 16;             // 4 MB
    float* out   = (float*)d_out;

    hipMemsetAsync(bucketCursor, 0, NBUCK * 4, stream);

    const int tb = 256;
    binA_kernel<<<(E + CHUNK - 1) / CHUNK, 512, 0, stream>>>(src, dst, ew, bucketCursor, coarse, E);
    bscan_kernel<<<1, NBUCK, 0, stream>>>(bucketCursor, bucketBase, row, N, E);
    binB_kernel<<<NBUCK, 512, 0, stream>>>(bucketCursor, bucketBase, coarse, edata, row, dinv, tcnt);
    pack_kernel<<<(N + tb - 1) / tb, tb, 0, stream>>>(X, dinv, Xp, N);
    aggA_kernel<<<N / 256, 512, 0, stream>>>(row, tcnt, edata, Xp, W1, b1, W2, h2);
    aggB_kernel<<<N / 256, 512, 0, stream>>>(row, tcnt, edata, dinv, h2, agg2);
    pool_head_kernel<<<G, tb, 0, stream>>>(agg2, b2, batching, N,
                                           Wp1, bp1, Wp2, bp2, Wp3, bp3,
                                           Wt1, bt1, Wt2, bt2, Wt3, bt3, out);
}